// Round 3
// baseline (139.309 us; speedup 1.0000x reference)
//
#include <hip/hip_runtime.h>
#include <hip/hip_bf16.h>

// MarketEncoder collapses analytically:
//   feats = (feats - mean_t(feats)) / std_t(feats)   (standardize over time)
//   fmean = mean_t(feats) == 0 exactly  =>  h = bp for every batch row
//   => out[b,:] = b2 + W2 @ gelu_exact(W1 @ bp + b1)  broadcast over B=64 rows.
// Time-series inputs (close/high/low/open/volume) and Wp never affect the output.
//
// Dtype evidence (3 rounds):
//  - R1: reading weights as bf16 -> NaN (fp32 low half-words hit exp 0xFF ->
//    Inf -> gelu NaN). Inputs are fp32.
//  - R2: correct fp32 values stored as bf16 gave absmax 0.0482 — exactly the
//    fingerprint of packing 2 bf16 per fp32 slot (ref[m] vs ours[(2m+1)%256],
//    predicted ~0.05; second half zeros -> 0.036). Output buffer is fp32.
//    (The "(bf16, ...)" assert label is a hardcoded f-string, not the decode.)
//
// Input order (setup_inputs dict): 0=close 1=high 2=low 3=open_price 4=volume
//                                  5=Wp 6=bp 7=W1 8=b1 9=W2 10=b2

#define ME_DIM 256
#define ME_HID 512
#define ME_B   64

// One block per batch row; each block redundantly computes the constant
// 256-vector (reads W1+W2 = 1 MB, L2-deduped across blocks) and writes its
// own coalesced fp32 row. No inter-block dependency, no reductions.
__global__ __launch_bounds__(256) void market_encoder_const_kernel(
    const float* __restrict__ bp,   // [256]
    const float* __restrict__ W1,   // [512, 256] row-major
    const float* __restrict__ b1,   // [512]
    const float* __restrict__ W2,   // [256, 512] row-major
    const float* __restrict__ b2,   // [256]
    float* __restrict__ out)        // [64, 256] fp32
{
    __shared__ float s_bp[ME_DIM];
    __shared__ float s_g[ME_HID];

    const int tid = threadIdx.x;

    s_bp[tid] = bp[tid];
    __syncthreads();

    // Each thread computes 2 hidden units: g[j] = gelu_exact(b1[j] + W1[j,:]·bp)
    #pragma unroll
    for (int r = 0; r < 2; ++r) {
        const int j = tid + r * ME_DIM;
        const float* __restrict__ w = W1 + j * ME_DIM;
        float acc = b1[j];
        for (int k = 0; k < ME_DIM; ++k) {
            acc += w[k] * s_bp[k];               // s_bp: all-lane LDS broadcast
        }
        // exact GELU (approximate=False): 0.5*x*(1+erf(x/sqrt(2)))
        s_g[j] = 0.5f * acc * (1.0f + erff(acc * 0.70710678118654752440f));
    }
    __syncthreads();

    // Each thread computes one output dim: out_d = b2[d] + W2[d,:]·g
    const int d = tid;
    const float* __restrict__ w2 = W2 + d * ME_HID;
    float acc = b2[d];
    for (int j = 0; j < ME_HID; ++j) {
        acc += w2[j] * s_g[j];                   // LDS broadcast
    }

    // Block b writes batch row b (256 consecutive fp32 -> coalesced).
    out[blockIdx.x * ME_DIM + d] = acc;
}

extern "C" void kernel_launch(void* const* d_in, const int* in_sizes, int n_in,
                              void* d_out, int out_size, void* d_ws, size_t ws_size,
                              hipStream_t stream) {
    (void)in_sizes; (void)n_in; (void)out_size; (void)d_ws; (void)ws_size;

    const float* bp = (const float*)d_in[6];
    const float* W1 = (const float*)d_in[7];
    const float* b1 = (const float*)d_in[8];
    const float* W2 = (const float*)d_in[9];
    const float* b2 = (const float*)d_in[10];
    float* out = (float*)d_out;

    market_encoder_const_kernel<<<ME_B, 256, 0, stream>>>(bp, W1, b1, W2, b2, out);
}